// Round 2
// baseline (648.812 us; speedup 1.0000x reference)
//
#include <hip/hip_runtime.h>
#include <math.h>

#define EPS 1e-15f
#define D 128
#define WPOS 5
#define WNEG 10
#define NSAMP (WPOS + WNEG)
#define NTYPES 4

__global__ __launch_bounds__(256) void mp2v_kernel(
    const float* __restrict__ start_embeds,
    const float* __restrict__ end_embeds,
    const int* __restrict__ start_node,
    const int* __restrict__ pos_samples,
    const int* __restrict__ neg_samples,
    const int* __restrict__ node_types,
    float* __restrict__ out,
    int nrows)
{
    const int lane = threadIdx.x & 63;
    const int row  = blockIdx.x * (blockDim.x >> 6) + (threadIdx.x >> 6);
    if (row >= nrows) return;

    // Wave-uniform scalars (same-address loads broadcast in one request)
    const int snode = start_node[row];
    const int t     = node_types[snode];

    // Lanes 0..14 fetch the 15 sample indices; broadcast later via shfl
    int myidx = 0;
    if (lane < WPOS)        myidx = pos_samples[row * WPOS + lane];
    else if (lane < NSAMP)  myidx = neg_samples[row * WNEG + (lane - WPOS)];

    // Start embedding: 64 lanes x float2 = 512 B coalesced
    const float2* __restrict__ sp = (const float2*)(start_embeds + (size_t)snode * D);
    const float2 s2 = sp[lane];

    // Issue all 15 end-row gathers up front (latency hiding via ILP)
    float2 e[NSAMP];
#pragma unroll
    for (int s = 0; s < NSAMP; ++s) {
        const int idx = __shfl(myidx, s);
        const float2* rp = (const float2*)(end_embeds + ((size_t)idx * NTYPES + t) * D);
        e[s] = rp[lane];
    }

    float posAcc = 0.f;
    float nl[WNEG];
#pragma unroll
    for (int s = 0; s < NSAMP; ++s) {
        // Per-lane partial dot, then 64-lane butterfly reduce
        float p = e[s].x * s2.x + e[s].y * s2.y;
        p += __shfl_xor(p, 32);
        p += __shfl_xor(p, 16);
        p += __shfl_xor(p, 8);
        p += __shfl_xor(p, 4);
        p += __shfl_xor(p, 2);
        p += __shfl_xor(p, 1);

        // Mirror the reference fp32 formula EXACTLY, including the
        // 1 - sigmoid cancellation (flushes to 0 for p >~ 16.64, matching
        // the fp32 numpy/jax reference). Precise expf/logf (~1 ulp).
        const float pr = 1.0f / (1.0f + expf(-p));
        if (s < WPOS) {
            posAcc += logf(pr + EPS);          // sequential, same order as np (n<8)
        } else {
            nl[s - WPOS] = logf(1.0f - pr + EPS);
        }
    }

    // numpy pairwise order for the 10 neg terms: tree of first 8, then +a8, +a9
    float negAcc = ((nl[0] + nl[1]) + (nl[2] + nl[3]))
                 + ((nl[4] + nl[5]) + (nl[6] + nl[7]));
    negAcc += nl[8];
    negAcc += nl[9];

    if (lane == 0)
        out[row] = -(posAcc / 5.0f) - (negAcc / 10.0f);
}

extern "C" void kernel_launch(void* const* d_in, const int* in_sizes, int n_in,
                              void* d_out, int out_size, void* d_ws, size_t ws_size,
                              hipStream_t stream) {
    const float* start_embeds = (const float*)d_in[0];
    const float* end_embeds   = (const float*)d_in[1];
    const int*   start_node   = (const int*)d_in[2];
    const int*   pos_samples  = (const int*)d_in[3];
    const int*   neg_samples  = (const int*)d_in[4];
    const int*   node_types   = (const int*)d_in[5];
    float* out = (float*)d_out;

    const int nrows = out_size;              // B = 131072 (loss is [B])
    const int wavesPerBlock = 256 / 64;
    const int blocks = (nrows + wavesPerBlock - 1) / wavesPerBlock;
    mp2v_kernel<<<blocks, 256, 0, stream>>>(start_embeds, end_embeds, start_node,
                                            pos_samples, neg_samples, node_types,
                                            out, nrows);
}

// Round 3
// 640.906 us; speedup vs baseline: 1.0123x; 1.0123x over previous
//
#include <hip/hip_runtime.h>
#include <math.h>

#define EPS 1e-15f
#define D 128
#define NTYPES 4

// One wave per row. Each half-wave (32 lanes) owns one sample per iteration:
// sample s = 2*i + half, i = 0..7 (s=15 is a discarded duplicate of s=14).
// Lane m (= lane&31) loads float4 = elements 4m..4m+3 -> one dwordx4 per lane,
// 1 KB per wave-wide instruction (2 gathered rows) for max bytes-in-flight.
__global__ __launch_bounds__(256) void mp2v_kernel(
    const float* __restrict__ start_embeds,
    const float* __restrict__ end_embeds,
    const int* __restrict__ start_node,
    const int* __restrict__ pos_samples,
    const int* __restrict__ neg_samples,
    const int* __restrict__ node_types,
    float* __restrict__ out,
    int nrows)
{
    const int lane = threadIdx.x & 63;
    const int half = lane >> 5;            // 0 or 1
    const int m    = lane & 31;            // lane within half-wave
    const int row  = blockIdx.x * (blockDim.x >> 6) + (threadIdx.x >> 6);
    if (row >= nrows) return;

    // Wave-uniform scalars
    const int snode = start_node[row];
    const int t     = node_types[snode];

    // Lanes 0..14 fetch the 15 sample indices; broadcast via bpermute
    int myidx = 0;
    if (lane < 5)        myidx = pos_samples[row * 5 + lane];
    else if (lane < 15)  myidx = neg_samples[row * 10 + (lane - 5)];

    // Start embedding fragment: 4 consecutive floats per lane (halves duplicate,
    // same cache lines)
    const float4 s4 = ((const float4*)(start_embeds + (size_t)snode * D))[m];

    // Issue all 8 end-row gather instructions up front (8 KB in flight per wave)
    float4 e4[8];
#pragma unroll
    for (int i = 0; i < 8; ++i) {
        int src = 2 * i + half;
        if (src > 14) src = 14;                        // pad slot duplicates s=14
        const int idx = __shfl(myidx, src);
        e4[i] = ((const float4*)(end_embeds + ((size_t)idx * NTYPES + t) * D))[m];
    }

    float posAcc = 0.0f, negAcc = 0.0f;
#pragma unroll
    for (int i = 0; i < 8; ++i) {
        // Unfused products (matches numpy's mul-then-add), balanced pairwise sum
        const float p0 = __fmul_rn(e4[i].x, s4.x);
        const float p1 = __fmul_rn(e4[i].y, s4.y);
        const float p2 = __fmul_rn(e4[i].z, s4.z);
        const float p3 = __fmul_rn(e4[i].w, s4.w);
        float p = __fadd_rn(__fadd_rn(p0, p1), __fadd_rn(p2, p3));
        // 5-level butterfly within each 32-lane half (serves 2 samples/instr)
        p = __fadd_rn(p, __shfl_xor(p, 1));
        p = __fadd_rn(p, __shfl_xor(p, 2));
        p = __fadd_rn(p, __shfl_xor(p, 4));
        p = __fadd_rn(p, __shfl_xor(p, 8));
        p = __fadd_rn(p, __shfl_xor(p, 16));

        // Reference fp32 formula EXACTLY, including the 1-sigmoid cancellation
        // (flushes to log(1e-15) for p >~ 16.64, matching the fp32 np ref).
        const float pr = 1.0f / (1.0f + expf(-p));
        const int  s     = 2 * i + half;
        const bool isPos = (s < 5);
        const bool valid = (s < 15);
        const float arg = isPos ? pr : (1.0f - pr);
        const float lg  = logf(arg + EPS);
        posAcc += (isPos && valid) ? lg : 0.0f;
        negAcc += (!isPos && valid) ? lg : 0.0f;
    }

    // Combine the two halves (branchless; all lanes converge)
    posAcc += __shfl_xor(posAcc, 32);
    negAcc += __shfl_xor(negAcc, 32);

    if (lane == 0)
        out[row] = -(posAcc / 5.0f) - (negAcc / 10.0f);
}

extern "C" void kernel_launch(void* const* d_in, const int* in_sizes, int n_in,
                              void* d_out, int out_size, void* d_ws, size_t ws_size,
                              hipStream_t stream) {
    const float* start_embeds = (const float*)d_in[0];
    const float* end_embeds   = (const float*)d_in[1];
    const int*   start_node   = (const int*)d_in[2];
    const int*   pos_samples  = (const int*)d_in[3];
    const int*   neg_samples  = (const int*)d_in[4];
    const int*   node_types   = (const int*)d_in[5];
    float* out = (float*)d_out;

    const int nrows = out_size;              // B = 131072 (loss is [B])
    const int wavesPerBlock = 256 / 64;
    const int blocks = (nrows + wavesPerBlock - 1) / wavesPerBlock;
    mp2v_kernel<<<blocks, 256, 0, stream>>>(start_embeds, end_embeds, start_node,
                                            pos_samples, neg_samples, node_types,
                                            out, nrows);
}